// Round 2
// baseline (322.184 us; speedup 1.0000x reference)
//
#include <hip/hip_runtime.h>

// Problem constants (from reference)
#define B_   16
#define L_   6
#define C_   2
#define H_   352
#define W_   704
#define HW_  (H_ * W_)          // 247808
#define NIMG (B_ * L_)          // 96
#define NMASK (NIMG * HW_)      // 23,789,568
#define THRESH 0.01f

// Tile config
#define TW 64
#define TH 16
#define HALO 2
#define TILE_W (TW + 2 * HALO)  // 68
#define TILE_H (TH + 2 * HALO)  // 20

__global__ __launch_bounds__(256) void comm_fused_kernel(
    const float* __restrict__ x,      // (B,L,C,H,W)
    const float* __restrict__ gw,     // (1,1,5,5)
    float* __restrict__ out_mask,     // (B*L,1,H,W)
    float* __restrict__ rate,         // scalar
    float* __restrict__ out_sm)       // (B,L,1,H,W)
{
    __shared__ float tile[TILE_H][TILE_W];

    const int img = blockIdx.z;                 // 0..95  (= b*L + l)
    const int w0  = blockIdx.x * TW;
    const int h0  = blockIdx.y * TH;
    const int tid = threadIdx.y * 64 + threadIdx.x;

    const float* xb = x + (size_t)img * (C_ * HW_);

    // Stage conf = max(sigmoid(ch0), sigmoid(ch1)) with zero-padded halo
    for (int i = tid; i < TILE_H * TILE_W; i += 256) {
        int r = i / TILE_W, c = i % TILE_W;
        int h = h0 + r - HALO, w = w0 + c - HALO;
        float v = 0.f;
        if ((unsigned)h < (unsigned)H_ && (unsigned)w < (unsigned)W_) {
            float a  = xb[h * W_ + w];
            float b  = xb[HW_ + h * W_ + w];
            float sa = 1.f / (1.f + __expf(-a));
            float sb = 1.f / (1.f + __expf(-b));
            v = fmaxf(sa, sb);
        }
        tile[r][c] = v;
    }

    // Gaussian taps (uniform address -> scalar loads, L1/L2 resident)
    float g[25];
#pragma unroll
    for (int i = 0; i < 25; ++i) g[i] = gw[i];

    __syncthreads();

    const int tx = threadIdx.x;          // 0..63
    const int ty = threadIdx.y;          // 0..3
    const bool ego = (img % L_) == 0;

    float cnt = 0.f;
#pragma unroll
    for (int rr = 0; rr < 4; ++rr) {
        int ly = ty + rr * 4;            // rows {ty, ty+4, ty+8, ty+12}
        float acc = 0.f;
#pragma unroll
        for (int dy = 0; dy < 5; ++dy)
#pragma unroll
            for (int dx = 0; dx < 5; ++dx)
                acc = fmaf(g[dy * 5 + dx], tile[ly + dy][tx + dx], acc);

        int h = h0 + ly, w = w0 + tx;
        int idx = img * HW_ + h * W_ + w;
        out_sm[idx] = acc;
        float m = (acc > THRESH) ? 1.f : 0.f;
        cnt += m;                         // rate counts PRE-ego mask
        out_mask[idx] = ego ? 1.f : m;
    }

    // Block reduction of mask count -> one atomicAdd per block
#pragma unroll
    for (int off = 32; off >= 1; off >>= 1)
        cnt += __shfl_down(cnt, off, 64);

    __shared__ float wsum[4];
    if ((tid & 63) == 0) wsum[tid >> 6] = cnt;
    __syncthreads();
    if (tid == 0) {
        float s = wsum[0] + wsum[1] + wsum[2] + wsum[3];
        atomicAdd(rate, s * (1.f / (float)NMASK));
    }
}

extern "C" void kernel_launch(void* const* d_in, const int* in_sizes, int n_in,
                              void* d_out, int out_size, void* d_ws, size_t ws_size,
                              hipStream_t stream) {
    const float* x  = (const float*)d_in[0];
    const float* gw = (const float*)d_in[1];
    float* out      = (float*)d_out;

    float* mask_out = out;               // 23,789,568 elements
    float* rate_out = out + NMASK;       // 1 element
    float* sm_out   = out + NMASK + 1;   // 23,789,568 elements

    // Zero the rate accumulator (graph-capture safe)
    hipMemsetAsync(rate_out, 0, sizeof(float), stream);

    dim3 grid(W_ / TW, H_ / TH, NIMG);   // (11, 22, 96)
    dim3 block(64, 4, 1);
    comm_fused_kernel<<<grid, block, 0, stream>>>(x, mask_out ? gw : gw, mask_out, rate_out, sm_out);
}

// Round 5
// 140.081 us; speedup vs baseline: 2.3000x; 2.3000x over previous
//
#include <hip/hip_runtime.h>

// Problem constants
#define B_   16
#define L_   6
#define H_   352
#define W_   704
#define HW_  (H_ * W_)          // 247808
#define NIMG (B_ * L_)          // 96
#define NMASK (NIMG * HW_)      // 23,789,568
#define THRESH 0.01f

// Tile config: 176 x 16 outputs, staged 184 x 20 (f4-aligned halo)
#define TW   176
#define TH   16
#define SW   184                // staged width  = TW + 8 (halo 2 padded to f4)
#define SW4  46                 // SW / 4
#define SH   20                 // TH + 4
#define OW4  44                 // TW / 4

__device__ __forceinline__ float sig(float v) {
    return 1.f / (1.f + __expf(-v));
}

__global__ __launch_bounds__(256) void comm_fused_v2(
    const float* __restrict__ x,      // (B,L,2,H,W)
    const float* __restrict__ gw,     // (1,1,5,5)
    float* __restrict__ out_mask,     // (B*L,1,H,W)
    float* __restrict__ rate,         // scalar
    float* __restrict__ out_sm)       // (B,L,1,H,W), base 4B-misaligned vs 16B
{
    __shared__ float tile[SH][SW];    // conf with halo
    __shared__ float vbuf[TH][SW];    // vertical-conv result
    __shared__ float wsum[4];

    const int img = blockIdx.z;                 // 0..95
    const int w0  = blockIdx.x * TW;
    const int h0  = blockIdx.y * TH;
    const int tid = threadIdx.x;                // block = 256x1

    const float* xb = x + (size_t)img * (2 * HW_);

    // Separable weights: g2d[i][j] == u[i] * v[j] exactly (outer product)
    float u[5], v[5];
    {
        const float g12 = gw[12];
        #pragma unroll
        for (int i = 0; i < 5; ++i) u[i] = gw[i * 5 + 2];
        #pragma unroll
        for (int j = 0; j < 5; ++j) v[j] = gw[2 * 5 + j] / g12;
    }

    // ---- Phase 1: stage conf = max(sigmoid(ch0), sigmoid(ch1)), f4 loads ----
    for (int j = tid; j < SH * SW4; j += 256) {
        const int r  = j / SW4, c4 = j % SW4;
        const int h  = h0 - 2 + r;
        const int w  = w0 - 4 + 4 * c4;          // 16B aligned
        float4 cf = make_float4(0.f, 0.f, 0.f, 0.f);
        if ((unsigned)h < (unsigned)H_ && w >= 0 && w <= W_ - 4) {
            const float4 a = *(const float4*)(xb + (size_t)h * W_ + w);
            const float4 b = *(const float4*)(xb + HW_ + (size_t)h * W_ + w);
            cf.x = fmaxf(sig(a.x), sig(b.x));
            cf.y = fmaxf(sig(a.y), sig(b.y));
            cf.z = fmaxf(sig(a.z), sig(b.z));
            cf.w = fmaxf(sig(a.w), sig(b.w));
        }
        *(float4*)&tile[r][4 * c4] = cf;
    }
    __syncthreads();

    // ---- Phase 2: vertical 5-tap conv (f4 math) ----
    for (int j = tid; j < TH * SW4; j += 256) {
        const int r = j / SW4, c4 = j % SW4;
        float4 acc = make_float4(0.f, 0.f, 0.f, 0.f);
        #pragma unroll
        for (int dy = 0; dy < 5; ++dy) {
            const float4 t = *(const float4*)&tile[r + dy][4 * c4];
            acc.x = fmaf(u[dy], t.x, acc.x);
            acc.y = fmaf(u[dy], t.y, acc.y);
            acc.z = fmaf(u[dy], t.z, acc.z);
            acc.w = fmaf(u[dy], t.w, acc.w);
        }
        *(float4*)&vbuf[r][4 * c4] = acc;
    }
    __syncthreads();

    // ---- Phase 3: horizontal 5-tap conv + outputs ----
    float cnt = 0.f;
    const bool ego = (img % L_) == 0;
    for (int j = tid; j < TH * OW4; j += 256) {
        const int r = j / OW4, c4 = j % OW4;
        float w12[12];
        *(float4*)&w12[0] = *(const float4*)&vbuf[r][4 * c4];
        *(float4*)&w12[4] = *(const float4*)&vbuf[r][4 * c4 + 4];
        *(float4*)&w12[8] = *(const float4*)&vbuf[r][4 * c4 + 8];
        float o[4];
        #pragma unroll
        for (int k = 0; k < 4; ++k) {
            float a = 0.f;
            #pragma unroll
            for (int dx = 0; dx < 5; ++dx)
                a = fmaf(v[dx], w12[2 + k + dx], a);
            o[k] = a;
        }
        const int h = h0 + r, w = w0 + 4 * c4;
        const size_t idx = (size_t)img * HW_ + (size_t)h * W_ + w;
        // smoothed: scalar stores (buffer base misaligned by 1 float)
        out_sm[idx + 0] = o[0];
        out_sm[idx + 1] = o[1];
        out_sm[idx + 2] = o[2];
        out_sm[idx + 3] = o[3];
        float4 m;
        m.x = (o[0] > THRESH) ? 1.f : 0.f;
        m.y = (o[1] > THRESH) ? 1.f : 0.f;
        m.z = (o[2] > THRESH) ? 1.f : 0.f;
        m.w = (o[3] > THRESH) ? 1.f : 0.f;
        cnt += m.x + m.y + m.z + m.w;        // rate counts PRE-ego force
        if (ego) m = make_float4(1.f, 1.f, 1.f, 1.f);
        *(float4*)(out_mask + idx) = m;      // 16B aligned
    }

    // ---- Rate reduction: one atomic per block ----
    #pragma unroll
    for (int off = 32; off >= 1; off >>= 1)
        cnt += __shfl_down(cnt, off, 64);
    if ((tid & 63) == 0) wsum[tid >> 6] = cnt;
    __syncthreads();
    if (tid == 0) {
        const float s = wsum[0] + wsum[1] + wsum[2] + wsum[3];
        atomicAdd(rate, s * (1.f / (float)NMASK));
    }
}

extern "C" void kernel_launch(void* const* d_in, const int* in_sizes, int n_in,
                              void* d_out, int out_size, void* d_ws, size_t ws_size,
                              hipStream_t stream) {
    const float* x  = (const float*)d_in[0];
    const float* gw = (const float*)d_in[1];
    float* out      = (float*)d_out;

    float* mask_out = out;               // 23,789,568
    float* rate_out = out + NMASK;       // 1
    float* sm_out   = out + NMASK + 1;   // 23,789,568

    hipMemsetAsync(rate_out, 0, sizeof(float), stream);

    dim3 grid(W_ / TW, H_ / TH, NIMG);   // (4, 22, 96) = 8448 blocks
    dim3 block(256, 1, 1);
    comm_fused_v2<<<grid, block, 0, stream>>>(x, gw, mask_out, rate_out, sm_out);
}

// Round 6
// 136.682 us; speedup vs baseline: 2.3572x; 1.0249x over previous
//
#include <hip/hip_runtime.h>

// Problem constants
#define B_   16
#define L_   6
#define H_   352
#define W_   704
#define HW_  (H_ * W_)          // 247808
#define NIMG (B_ * L_)          // 96
#define NMASK (NIMG * HW_)      // 23,789,568
#define THRESH 0.01f

// Tile: 176 x 16 outputs; staged (16+4) x 184 cols, stride padded to 188
#define TW  176
#define TH  16
#define SH  (TH + 4)            // 20
#define SB  46                  // staged float4 blocks per row (cols w0-4 .. w0+179)
#define SWP 188                 // padded LDS row stride (floats)

__global__ __launch_bounds__(256, 8) void comm_fused_v3(
    const float* __restrict__ x,      // (B,L,2,H,W)
    const float* __restrict__ gw,     // (1,1,5,5)
    float* __restrict__ out_mask,     // (B*L,1,H,W)
    float* __restrict__ rate,         // scalar
    float* __restrict__ out_sm)       // (B,L,1,H,W)
{
    __shared__ float tile[SH][SWP];   // conf with halo (14.8 KB)
    __shared__ float wsum[4];

    const int img = blockIdx.z;
    const int w0  = blockIdx.x * TW;
    const int h0  = blockIdx.y * TH;
    const int tid = threadIdx.x;

    const float* xb = x + (size_t)img * (2 * HW_);

    // Exact separable weights: g2d[i][j] == u[i] * hv[j] (rank-1 outer product)
    float u[5], hv[5];
    {
        const float g12 = gw[12];
        #pragma unroll
        for (int i = 0; i < 5; ++i) u[i] = gw[i * 5 + 2];
        #pragma unroll
        for (int j = 0; j < 5; ++j) hv[j] = gw[10 + j] / g12;
    }

    // ---- Phase 1: stage conf = sigmoid(max(ch0, ch1)) (monotone sigmoid!) ----
    const bool interior = (h0 >= 2) && (h0 + TH + 2 <= H_) &&
                          (w0 >= 4) && (w0 + TW + 4 <= W_);
    if (interior) {
        #pragma unroll
        for (int it = 0; it < 4; ++it) {
            const int j = tid + it * 256;
            if (j < SH * SB) {
                const int r = j / SB, c = j - r * SB;
                const size_t off = (size_t)(h0 - 2 + r) * W_ + (w0 - 4 + 4 * c);
                const float4 a = *(const float4*)(xb + off);
                const float4 b = *(const float4*)(xb + HW_ + off);
                float4 cf;
                cf.x = 1.f / (1.f + __expf(-fmaxf(a.x, b.x)));
                cf.y = 1.f / (1.f + __expf(-fmaxf(a.y, b.y)));
                cf.z = 1.f / (1.f + __expf(-fmaxf(a.z, b.z)));
                cf.w = 1.f / (1.f + __expf(-fmaxf(a.w, b.w)));
                *(float4*)&tile[r][4 * c] = cf;
            }
        }
    } else {
        for (int j = tid; j < SH * SB; j += 256) {
            const int r = j / SB, c = j - r * SB;
            const int h = h0 - 2 + r;
            const int w = w0 - 4 + 4 * c;       // multiple of 4; OOB quads fully OOB
            float4 cf = make_float4(0.f, 0.f, 0.f, 0.f);
            if ((unsigned)h < (unsigned)H_ && (unsigned)w < (unsigned)W_) {
                const size_t off = (size_t)h * W_ + w;
                const float4 a = *(const float4*)(xb + off);
                const float4 b = *(const float4*)(xb + HW_ + off);
                cf.x = 1.f / (1.f + __expf(-fmaxf(a.x, b.x)));
                cf.y = 1.f / (1.f + __expf(-fmaxf(a.y, b.y)));
                cf.z = 1.f / (1.f + __expf(-fmaxf(a.z, b.z)));
                cf.w = 1.f / (1.f + __expf(-fmaxf(a.w, b.w)));
            }
            *(float4*)&tile[r][4 * c] = cf;
        }
    }
    __syncthreads();

    // ---- Phase 2: vertical conv in regs + horizontal via lane shuffles ----
    const int wave = tid >> 6, lane = tid & 63;
    const bool ego = (img % L_) == 0;
    float cnt = 0.f;

    if (lane < SB) {
        #pragma unroll
        for (int rr = 0; rr < 4; ++rr) {
            const int r = wave * 4 + rr;       // wave handles 4 rows
            float4 v = make_float4(0.f, 0.f, 0.f, 0.f);
            #pragma unroll
            for (int dy = 0; dy < 5; ++dy) {
                const float4 t = *(const float4*)&tile[r + dy][4 * lane];
                v.x = fmaf(u[dy], t.x, v.x);
                v.y = fmaf(u[dy], t.y, v.y);
                v.z = fmaf(u[dy], t.z, v.z);
                v.w = fmaf(u[dy], t.w, v.w);
            }
            // lane l's v covers output cols 4(l-1)..4(l-1)+3; halo from neighbors
            const float lz = __shfl_up(v.z, 1, 64);    // col -2
            const float lw = __shfl_up(v.w, 1, 64);    // col -1
            const float rx = __shfl_down(v.x, 1, 64);  // col +4
            const float ry = __shfl_down(v.y, 1, 64);  // col +5
            if (lane >= 1 && lane < SB - 1) {
                float s[8] = { lz, lw, v.x, v.y, v.z, v.w, rx, ry };
                float o[4];
                #pragma unroll
                for (int k = 0; k < 4; ++k) {
                    float a = hv[0] * s[k];
                    #pragma unroll
                    for (int dx = 1; dx < 5; ++dx)
                        a = fmaf(hv[dx], s[k + dx], a);
                    o[k] = a;
                }
                const int h = h0 + r;
                const int w = w0 + 4 * (lane - 1);
                const size_t idx = (size_t)img * HW_ + (size_t)h * W_ + w;
                // smoothed buffer base is 4B-misaligned vs 16B -> scalar stores
                out_sm[idx + 0] = o[0];
                out_sm[idx + 1] = o[1];
                out_sm[idx + 2] = o[2];
                out_sm[idx + 3] = o[3];
                float4 m;
                m.x = (o[0] > THRESH) ? 1.f : 0.f;
                m.y = (o[1] > THRESH) ? 1.f : 0.f;
                m.z = (o[2] > THRESH) ? 1.f : 0.f;
                m.w = (o[3] > THRESH) ? 1.f : 0.f;
                cnt += m.x + m.y + m.z + m.w;   // rate counted PRE-ego force
                if (ego) m = make_float4(1.f, 1.f, 1.f, 1.f);
                *(float4*)(out_mask + idx) = m; // 16B aligned
            }
        }
    }

    // ---- Rate: wave shuffle-reduce -> block -> one atomic ----
    #pragma unroll
    for (int off = 32; off >= 1; off >>= 1)
        cnt += __shfl_down(cnt, off, 64);
    if ((tid & 63) == 0) wsum[tid >> 6] = cnt;
    __syncthreads();
    if (tid == 0) {
        const float s = wsum[0] + wsum[1] + wsum[2] + wsum[3];
        atomicAdd(rate, s * (1.f / (float)NMASK));
    }
}

extern "C" void kernel_launch(void* const* d_in, const int* in_sizes, int n_in,
                              void* d_out, int out_size, void* d_ws, size_t ws_size,
                              hipStream_t stream) {
    const float* x  = (const float*)d_in[0];
    const float* gw = (const float*)d_in[1];
    float* out      = (float*)d_out;

    float* mask_out = out;               // 23,789,568
    float* rate_out = out + NMASK;       // 1
    float* sm_out   = out + NMASK + 1;   // 23,789,568

    hipMemsetAsync(rate_out, 0, sizeof(float), stream);

    dim3 grid(W_ / TW, H_ / TH, NIMG);   // (4, 22, 96) = 8448 blocks
    dim3 block(256, 1, 1);
    comm_fused_v3<<<grid, block, 0, stream>>>(x, gw, mask_out, rate_out, sm_out);
}

// Round 8
// 136.394 us; speedup vs baseline: 2.3621x; 1.0021x over previous
//
#include <hip/hip_runtime.h>

// Problem constants
#define B_   16
#define L_   6
#define H_   352
#define W_   704
#define HW_  (H_ * W_)          // 247808
#define NIMG (B_ * L_)          // 96
#define NMASK (NIMG * HW_)      // 23,789,568
#define THRESH 0.01f

// Work decomposition: wave = (img, strip, chunk)
#define NQ     176              // W/4 quads per row
#define NSTRIP 3                // strips of 62 output quads (last: 52)
#define NCHUNK 22
#define CH     16               // output rows per chunk (22*16 = 352)
#define ITEMS  (NIMG * NSTRIP * NCHUNK)   // 6336 waves
#define NBLK   (ITEMS / 4)                // 1584 blocks of 4 waves

// OOB sentinel: sigmoid(-1e30) == 0 exactly (expf(1e30)=inf -> 1/(1+inf)=0),
// reproducing the zero-padded *confidence* map of the reference conv.
#define OOBV  -1.0e30f

__device__ __forceinline__ float4 sig4max(float4 a, float4 b) {
    float4 c;
    c.x = 1.f / (1.f + __expf(-fmaxf(a.x, b.x)));
    c.y = 1.f / (1.f + __expf(-fmaxf(a.y, b.y)));
    c.z = 1.f / (1.f + __expf(-fmaxf(a.z, b.z)));
    c.w = 1.f / (1.f + __expf(-fmaxf(a.w, b.w)));
    return c;
}

__device__ __forceinline__ void raw_load(const float* __restrict__ xb,
                                         int h, int iq, float4& a, float4& b) {
    if ((unsigned)h < (unsigned)H_ && (unsigned)iq < (unsigned)NQ) {
        const size_t off = (size_t)h * W_ + 4 * iq;
        a = *(const float4*)(xb + off);
        b = *(const float4*)(xb + HW_ + off);
    } else {
        a = make_float4(OOBV, OOBV, OOBV, OOBV);
        b = make_float4(OOBV, OOBV, OOBV, OOBV);
    }
}

__global__ __launch_bounds__(256) void comm_fused_v4(
    const float* __restrict__ x,      // (B,L,2,H,W)
    const float* __restrict__ gw,     // (1,1,5,5)
    float* __restrict__ out_mask,     // (B*L,1,H,W)
    float* __restrict__ rate,         // scalar
    float* __restrict__ out_sm)       // (B,L,1,H,W)
{
    const int wave = threadIdx.x >> 6;
    const int lane = threadIdx.x & 63;
    const int item = blockIdx.x * 4 + wave;          // < ITEMS (exact)

    const int img   = item / (NSTRIP * NCHUNK);
    const int rem   = item % (NSTRIP * NCHUNK);
    const int strip = rem / NCHUNK;                  // chunks adjacent -> L2 halo reuse
    const int chunk = rem % NCHUNK;

    const int hA = chunk * CH;
    const int iq = strip * 62 - 1 + lane;            // input quad this lane loads
    const bool outlane = (lane >= 1) && (lane <= 62) && (iq < NQ);

    const float* xb = x + (size_t)img * (2 * HW_);

    // Exact separable weights: g2d[i][j] == u[i] * hv[j]
    float u[5], hv[5];
    {
        const float g12 = gw[12];
        #pragma unroll
        for (int i = 0; i < 5; ++i) u[i] = gw[i * 5 + 2];
        #pragma unroll
        for (int j = 0; j < 5; ++j) hv[j] = gw[10 + j] / g12;
    }

    // Prologue: conf window rows hA-2..hA+1, raw prefetch row hA+2
    float4 c0, c1, c2, c3, c4, pa, pb;
    {
        float4 a0, b0, a1, b1, a2, b2, a3, b3;
        raw_load(xb, hA - 2, iq, a0, b0);
        raw_load(xb, hA - 1, iq, a1, b1);
        raw_load(xb, hA,     iq, a2, b2);
        raw_load(xb, hA + 1, iq, a3, b3);
        raw_load(xb, hA + 2, iq, pa, pb);
        c0 = sig4max(a0, b0);
        c1 = sig4max(a1, b1);
        c2 = sig4max(a2, b2);
        c3 = sig4max(a3, b3);
    }

    const bool ego = (img % L_) == 0;
    float cnt = 0.f;

    #pragma unroll 2
    for (int r = 0; r < CH; ++r) {
        const int h = hA + r;

        // Prefetch raw row h+3 (hides latency under this row's compute)
        float4 na, nb;
        raw_load(xb, h + 3, iq, na, nb);

        // Finish conf for row h+2
        c4 = sig4max(pa, pb);

        // Vertical 5-tap (registers)
        float4 v;
        v.x = u[0] * c0.x; v.y = u[0] * c0.y; v.z = u[0] * c0.z; v.w = u[0] * c0.w;
        v.x = fmaf(u[1], c1.x, v.x); v.y = fmaf(u[1], c1.y, v.y);
        v.z = fmaf(u[1], c1.z, v.z); v.w = fmaf(u[1], c1.w, v.w);
        v.x = fmaf(u[2], c2.x, v.x); v.y = fmaf(u[2], c2.y, v.y);
        v.z = fmaf(u[2], c2.z, v.z); v.w = fmaf(u[2], c2.w, v.w);
        v.x = fmaf(u[3], c3.x, v.x); v.y = fmaf(u[3], c3.y, v.y);
        v.z = fmaf(u[3], c3.z, v.z); v.w = fmaf(u[3], c3.w, v.w);
        v.x = fmaf(u[4], c4.x, v.x); v.y = fmaf(u[4], c4.y, v.y);
        v.z = fmaf(u[4], c4.z, v.z); v.w = fmaf(u[4], c4.w, v.w);

        // Horizontal halo from neighbor lanes
        const float lz = __shfl_up(v.z, 1);
        const float lw = __shfl_up(v.w, 1);
        const float rx = __shfl_down(v.x, 1);
        const float ry = __shfl_down(v.y, 1);

        if (outlane) {
            const float s[8] = { lz, lw, v.x, v.y, v.z, v.w, rx, ry };
            float o[4];
            #pragma unroll
            for (int k = 0; k < 4; ++k) {
                float a = hv[0] * s[k];
                #pragma unroll
                for (int dx = 1; dx < 5; ++dx)
                    a = fmaf(hv[dx], s[k + dx], a);
                o[k] = a;
            }
            const size_t idx = (size_t)img * HW_ + (size_t)h * W_ + 4 * iq;
            // smoothed base is 4B-misaligned vs 16B -> scalar stores
            out_sm[idx + 0] = o[0];
            out_sm[idx + 1] = o[1];
            out_sm[idx + 2] = o[2];
            out_sm[idx + 3] = o[3];
            float4 m;
            m.x = (o[0] > THRESH) ? 1.f : 0.f;
            m.y = (o[1] > THRESH) ? 1.f : 0.f;
            m.z = (o[2] > THRESH) ? 1.f : 0.f;
            m.w = (o[3] > THRESH) ? 1.f : 0.f;
            cnt += m.x + m.y + m.z + m.w;          // rate counted PRE-ego force
            if (ego) m = make_float4(1.f, 1.f, 1.f, 1.f);
            *(float4*)(out_mask + idx) = m;        // 16B aligned
        }

        // Shift window
        c0 = c1; c1 = c2; c2 = c3; c3 = c4;
        pa = na; pb = nb;
    }

    // Per-wave reduce -> one atomic per wave (no LDS, no barriers)
    #pragma unroll
    for (int off = 32; off >= 1; off >>= 1)
        cnt += __shfl_down(cnt, off);
    if (lane == 0)
        atomicAdd(rate, cnt * (1.f / (float)NMASK));
}

extern "C" void kernel_launch(void* const* d_in, const int* in_sizes, int n_in,
                              void* d_out, int out_size, void* d_ws, size_t ws_size,
                              hipStream_t stream) {
    const float* x  = (const float*)d_in[0];
    const float* gw = (const float*)d_in[1];
    float* out      = (float*)d_out;

    float* mask_out = out;               // 23,789,568
    float* rate_out = out + NMASK;       // 1
    float* sm_out   = out + NMASK + 1;   // 23,789,568

    hipMemsetAsync(rate_out, 0, sizeof(float), stream);

    dim3 grid(NBLK, 1, 1);               // 1584 blocks x 256 threads = 6336 waves
    dim3 block(256, 1, 1);
    comm_fused_v4<<<grid, block, 0, stream>>>(x, gw, mask_out, rate_out, sm_out);
}

// Round 9
// 131.238 us; speedup vs baseline: 2.4549x; 1.0393x over previous
//
#include <hip/hip_runtime.h>

// Problem constants
#define B_   16
#define L_   6
#define H_   352
#define W_   704
#define HW_  (H_ * W_)          // 247808
#define NIMG (B_ * L_)          // 96
#define NMASK (NIMG * HW_)      // 23,789,568
#define THRESH 0.01f

// Work decomposition: wave = (img, strip, chunk)
#define NQ     176              // W/4 quads per row
#define NSTRIP 3                // strips of 62 output quads (last: 52)
#define NCHUNK 22
#define CH     16               // output rows per chunk (22*16 = 352)
#define ITEMS  (NIMG * NSTRIP * NCHUNK)   // 6336 waves
#define NBLK   (ITEMS / 4)                // 1584 blocks of 4 waves

// OOB sentinel: sigmoid(-1e30) == 0 exactly -> zero-padded confidence map
#define OOBV  -1.0e30f

typedef float f4 __attribute__((ext_vector_type(4)));

__device__ __forceinline__ float4 sig4max(float4 a, float4 b) {
    float4 c;
    c.x = 1.f / (1.f + __expf(-fmaxf(a.x, b.x)));
    c.y = 1.f / (1.f + __expf(-fmaxf(a.y, b.y)));
    c.z = 1.f / (1.f + __expf(-fmaxf(a.z, b.z)));
    c.w = 1.f / (1.f + __expf(-fmaxf(a.w, b.w)));
    return c;
}

__device__ __forceinline__ void raw_load(const float* __restrict__ xb,
                                         int h, int iq, float4& a, float4& b) {
    if ((unsigned)h < (unsigned)H_ && (unsigned)iq < (unsigned)NQ) {
        const size_t off = (size_t)h * W_ + 4 * iq;
        a = *(const float4*)(xb + off);
        b = *(const float4*)(xb + HW_ + off);
    } else {
        a = make_float4(OOBV, OOBV, OOBV, OOBV);
        b = make_float4(OOBV, OOBV, OOBV, OOBV);
    }
}

__global__ __launch_bounds__(256) void comm_fused_v5(
    const float* __restrict__ x,      // (B,L,2,H,W)
    const float* __restrict__ gw,     // (1,1,5,5)
    float* __restrict__ out_mask,     // (B*L,1,H,W)
    float* __restrict__ rate,         // scalar
    float* __restrict__ sm_m1)        // out + NMASK  (= smoothed base - 1, 16B-aligned)
{
    const int wave = threadIdx.x >> 6;
    const int lane = threadIdx.x & 63;
    const int item = blockIdx.x * 4 + wave;

    const int img   = item / (NSTRIP * NCHUNK);
    const int rem   = item % (NSTRIP * NCHUNK);
    const int strip = rem / NCHUNK;
    const int chunk = rem % NCHUNK;

    const int hA = chunk * CH;
    const int iq = strip * 62 - 1 + lane;
    const bool outlane = (lane >= 1) && (lane <= 62) && (iq < NQ);
    const bool lead    = outlane && (iq > 0);      // can use shifted f4 store

    const float* xb = x + (size_t)img * (2 * HW_);
    float* __restrict__ sm = sm_m1 + 1;            // true smoothed base (scalar edge stores)

    // Exact separable weights: g2d[i][j] == u[i] * hv[j]
    float u[5], hv[5];
    {
        const float g12 = gw[12];
        #pragma unroll
        for (int i = 0; i < 5; ++i) u[i] = gw[i * 5 + 2];
        #pragma unroll
        for (int j = 0; j < 5; ++j) hv[j] = gw[10 + j] / g12;
    }

    // Prologue: issue 6 row-pair loads back-to-back (deep MLP), then sigmoids.
    float4 c0, c1, c2, c3, q0a, q0b, q1a, q1b;
    {
        float4 a0, b0, a1, b1, a2, b2, a3, b3;
        raw_load(xb, hA - 2, iq, a0, b0);
        raw_load(xb, hA - 1, iq, a1, b1);
        raw_load(xb, hA,     iq, a2, b2);
        raw_load(xb, hA + 1, iq, a3, b3);
        raw_load(xb, hA + 2, iq, q0a, q0b);   // raw pending, row h+2
        raw_load(xb, hA + 3, iq, q1a, q1b);   // raw pending, row h+3
        c0 = sig4max(a0, b0);
        c1 = sig4max(a1, b1);
        c2 = sig4max(a2, b2);
        c3 = sig4max(a3, b3);
    }

    const bool ego = (img % L_) == 0;
    float cnt = 0.f;

    for (int r = 0; r < CH; ++r) {
        const int h = hA + r;

        // Prefetch raw row h+4 (depth-2 pipeline)
        float4 q2a, q2b;
        raw_load(xb, h + 4, iq, q2a, q2b);

        // Finish conf for row h+2 (loads issued 2 iterations ago)
        const float4 c4 = sig4max(q0a, q0b);

        // Vertical 5-tap (registers)
        float4 v;
        v.x = u[0] * c0.x; v.y = u[0] * c0.y; v.z = u[0] * c0.z; v.w = u[0] * c0.w;
        v.x = fmaf(u[1], c1.x, v.x); v.y = fmaf(u[1], c1.y, v.y);
        v.z = fmaf(u[1], c1.z, v.z); v.w = fmaf(u[1], c1.w, v.w);
        v.x = fmaf(u[2], c2.x, v.x); v.y = fmaf(u[2], c2.y, v.y);
        v.z = fmaf(u[2], c2.z, v.z); v.w = fmaf(u[2], c2.w, v.w);
        v.x = fmaf(u[3], c3.x, v.x); v.y = fmaf(u[3], c3.y, v.y);
        v.z = fmaf(u[3], c3.z, v.z); v.w = fmaf(u[3], c3.w, v.w);
        v.x = fmaf(u[4], c4.x, v.x); v.y = fmaf(u[4], c4.y, v.y);
        v.z = fmaf(u[4], c4.z, v.z); v.w = fmaf(u[4], c4.w, v.w);

        // Horizontal halo from neighbor lanes
        const float lz = __shfl_up(v.z, 1);
        const float lw = __shfl_up(v.w, 1);
        const float rx = __shfl_down(v.x, 1);
        const float ry = __shfl_down(v.y, 1);

        // Horizontal conv on ALL lanes (lane 0's o[3] feeds lane 1's store)
        const float s0[8] = { lz, lw, v.x, v.y, v.z, v.w, rx, ry };
        float o0, o1, o2, o3;
        {
            float a;
            a = hv[0] * s0[0];
            a = fmaf(hv[1], s0[1], a); a = fmaf(hv[2], s0[2], a);
            a = fmaf(hv[3], s0[3], a); a = fmaf(hv[4], s0[4], a);
            o0 = a;
            a = hv[0] * s0[1];
            a = fmaf(hv[1], s0[2], a); a = fmaf(hv[2], s0[3], a);
            a = fmaf(hv[3], s0[4], a); a = fmaf(hv[4], s0[5], a);
            o1 = a;
            a = hv[0] * s0[2];
            a = fmaf(hv[1], s0[3], a); a = fmaf(hv[2], s0[4], a);
            a = fmaf(hv[3], s0[5], a); a = fmaf(hv[4], s0[6], a);
            o2 = a;
            a = hv[0] * s0[3];
            a = fmaf(hv[1], s0[4], a); a = fmaf(hv[2], s0[5], a);
            a = fmaf(hv[3], s0[6], a); a = fmaf(hv[4], s0[7], a);
            o3 = a;
        }
        const float o3l = __shfl_up(o3, 1);   // left neighbor's col 4iq-1 value

        if (outlane) {
            const size_t idx = (size_t)img * HW_ + (size_t)h * W_ + 4 * iq;

            // smoothed: shifted, 16B-aligned nontemporal f4 store
            if (lead) {
                f4 sv = { o3l, o0, o1, o2 };
                __builtin_nontemporal_store(sv, (f4*)(sm_m1 + idx));
            } else {  // iq == 0: cols 0..2 scalar (col -1 would hit previous row)
                __builtin_nontemporal_store(o0, sm + idx + 0);
                __builtin_nontemporal_store(o1, sm + idx + 1);
                __builtin_nontemporal_store(o2, sm + idx + 2);
            }
            if (iq == NQ - 1)                 // image last col (703)
                __builtin_nontemporal_store(o3, sm + idx + 3);

            // mask + rate (rate counted PRE-ego force)
            float m0 = (o0 > THRESH) ? 1.f : 0.f;
            float m1 = (o1 > THRESH) ? 1.f : 0.f;
            float m2 = (o2 > THRESH) ? 1.f : 0.f;
            float m3 = (o3 > THRESH) ? 1.f : 0.f;
            cnt += m0 + m1 + m2 + m3;
            f4 mv = ego ? (f4){1.f, 1.f, 1.f, 1.f} : (f4){m0, m1, m2, m3};
            __builtin_nontemporal_store(mv, (f4*)(out_mask + idx));
        }

        // Shift pipeline
        c0 = c1; c1 = c2; c2 = c3; c3 = c4;
        q0a = q1a; q0b = q1b; q1a = q2a; q1b = q2b;
    }

    // Per-wave reduce -> one atomic per wave (no LDS, no barriers)
    #pragma unroll
    for (int off = 32; off >= 1; off >>= 1)
        cnt += __shfl_down(cnt, off);
    if (lane == 0)
        atomicAdd(rate, cnt * (1.f / (float)NMASK));
}

extern "C" void kernel_launch(void* const* d_in, const int* in_sizes, int n_in,
                              void* d_out, int out_size, void* d_ws, size_t ws_size,
                              hipStream_t stream) {
    const float* x  = (const float*)d_in[0];
    const float* gw = (const float*)d_in[1];
    float* out      = (float*)d_out;

    float* mask_out = out;               // 23,789,568
    float* rate_out = out + NMASK;       // 1
    float* sm_m1    = out + NMASK;       // smoothed base - 1 (16B-aligned)

    // NOTE: rate slot overlaps sm_m1[0]; kernel writes sm_m1[0] only via the
    // iq==0 scalar path (sm+idx = sm_m1+1+idx, idx>=0) and the lead f4 store
    // at idx>=4 — sm_m1[0] itself is never touched by smoothed stores
    // (smallest lead idx is 4). rate atomicAdd is the sole writer. Order:
    // memset rate first, kernel writes smoothed elsewhere.
    hipMemsetAsync(rate_out, 0, sizeof(float), stream);

    dim3 grid(NBLK, 1, 1);               // 1584 blocks x 256 threads = 6336 waves
    dim3 block(256, 1, 1);
    comm_fused_v5<<<grid, block, 0, stream>>>(x, gw, mask_out, rate_out, sm_m1);
}